// Round 1
// baseline (803.094 us; speedup 1.0000x reference)
//
#include <hip/hip_runtime.h>

#define HD 64
#define BN_EPS 1e-5f

// ---------- CSR construction ----------

__global__ void k_deg(const int* __restrict__ dst, int* __restrict__ deg, int E) {
    int e = blockIdx.x * blockDim.x + threadIdx.x;
    if (e < E) atomicAdd(&deg[dst[e]], 1);
}

__global__ void k_dinv(const int* __restrict__ deg, float* __restrict__ dinv, int N) {
    int i = blockIdx.x * blockDim.x + threadIdx.x;
    if (i < N) dinv[i] = rsqrtf((float)(deg[i] + 1));  // +1 self-loop
}

// per-block inclusive scan of deg (256 elems/block), block totals to bsums
__global__ void k_scan1(const int* __restrict__ deg, int* __restrict__ incl,
                        int* __restrict__ bsums, int N) {
    __shared__ int s[256];
    int tid = threadIdx.x;
    int i = blockIdx.x * 256 + tid;
    int v = (i < N) ? deg[i] : 0;
    s[tid] = v;
    __syncthreads();
    for (int off = 1; off < 256; off <<= 1) {
        int t = (tid >= off) ? s[tid - off] : 0;
        __syncthreads();
        s[tid] += t;
        __syncthreads();
    }
    if (i < N) incl[i] = s[tid];
    if (tid == 255) bsums[blockIdx.x] = s[255];
}

// single-block scan of block sums -> exclusive offsets (nb <= 512)
__global__ void k_scan2(int* bsums, int nb) {
    __shared__ int s[512];
    int tid = threadIdx.x;
    int own = (tid < nb) ? bsums[tid] : 0;
    s[tid] = own;
    __syncthreads();
    for (int off = 1; off < 512; off <<= 1) {
        int t = (tid >= off) ? s[tid - off] : 0;
        __syncthreads();
        s[tid] += t;
        __syncthreads();
    }
    if (tid < nb) bsums[tid] = s[tid] - own;  // exclusive
}

__global__ void k_scan3(int* __restrict__ rowp, const int* __restrict__ deg,
                        const int* __restrict__ bsums, int N, int E) {
    int i = blockIdx.x * 256 + threadIdx.x;
    if (i < N) rowp[i] = rowp[i] - deg[i] + bsums[blockIdx.x];  // global exclusive
    if (i == 0) rowp[N] = E;
}

// bucket edges into CSR slots; payload = (src index bits, norm) as float2
__global__ void k_fill(const int* __restrict__ src, const int* __restrict__ dst,
                       const float* __restrict__ dinv, const int* __restrict__ rowp,
                       int* __restrict__ cur, float2* __restrict__ ed, int E) {
    int e = blockIdx.x * blockDim.x + threadIdx.x;
    if (e >= E) return;
    int s = src[e], d = dst[e];
    float nrm = dinv[s] * dinv[d];
    int pos = rowp[d] + atomicAdd(&cur[d], 1);
    ed[pos] = make_float2(__int_as_float(s), nrm);
}

// ---------- per-layer kernels ----------

// Out[i][f] = sum_k A[i][k] * W[f][k]   (h @ W^T), 64x64 W held in regs (lane = f)
__global__ __launch_bounds__(256) void k_gemm(const float* __restrict__ A,
                                              const float* __restrict__ W,
                                              float* __restrict__ Out, int N) {
    int lane = threadIdx.x & 63;
    float w[64];
    const float4* Wv = (const float4*)(W + lane * HD);
#pragma unroll
    for (int kk = 0; kk < 16; kk++) {
        float4 t = Wv[kk];
        w[4 * kk] = t.x; w[4 * kk + 1] = t.y; w[4 * kk + 2] = t.z; w[4 * kk + 3] = t.w;
    }
    int wid = (blockIdx.x * blockDim.x + threadIdx.x) >> 6;
    int nw = (gridDim.x * blockDim.x) >> 6;
    for (int i = wid; i < N; i += nw) {
        const float4* Av = (const float4*)(A + (size_t)i * HD);
        float a0 = 0.f, a1 = 0.f, a2 = 0.f, a3 = 0.f;
#pragma unroll
        for (int kk = 0; kk < 16; kk++) {
            float4 hv = Av[kk];  // wave-uniform broadcast load
            a0 = fmaf(hv.x, w[4 * kk], a0);
            a1 = fmaf(hv.y, w[4 * kk + 1], a1);
            a2 = fmaf(hv.z, w[4 * kk + 2], a2);
            a3 = fmaf(hv.w, w[4 * kk + 3], a3);
        }
        Out[(size_t)i * HD + lane] = (a0 + a1) + (a2 + a3);
    }
}

// one wave per node: gather CSR neighbors + self loop, +bias, relu,
// write pre-BN h, accumulate BN partial sums
__global__ __launch_bounds__(256) void k_agg(const int* __restrict__ rowp,
                                             const float2* __restrict__ ed,
                                             const float* __restrict__ dinv,
                                             const float* __restrict__ hW,
                                             const float* __restrict__ bias,
                                             float* __restrict__ out,
                                             float* __restrict__ stats, int N) {
    int lane = threadIdx.x & 63;
    int wid = (blockIdx.x * blockDim.x + threadIdx.x) >> 6;
    int nw = (gridDim.x * blockDim.x) >> 6;
    float bv = bias[lane];
    float bsum = 0.f, bsq = 0.f;
    for (int i = wid; i < N; i += nw) {
        int rs = rowp[i], re = rowp[i + 1];
        float di = dinv[i];
        float acc = di * di * hW[(size_t)i * HD + lane];  // self loop
        for (int e = rs; e < re; e++) {
            float2 m = ed[e];  // wave-uniform
            acc = fmaf(m.y, hW[(size_t)__float_as_int(m.x) * HD + lane], acc);
        }
        acc += bv;
        acc = fmaxf(acc, 0.f);
        out[(size_t)i * HD + lane] = acc;
        bsum += acc;
        bsq = fmaf(acc, acc, bsq);
    }
    __shared__ float s1[256], s2[256];
    s1[threadIdx.x] = bsum;
    s2[threadIdx.x] = bsq;
    __syncthreads();
    if (threadIdx.x < 64) {
        float a = s1[threadIdx.x] + s1[threadIdx.x + 64] + s1[threadIdx.x + 128] + s1[threadIdx.x + 192];
        float b = s2[threadIdx.x] + s2[threadIdx.x + 64] + s2[threadIdx.x + 128] + s2[threadIdx.x + 192];
        atomicAdd(&stats[threadIdx.x], a);
        atomicAdd(&stats[64 + threadIdx.x], b);
    }
}

// finalize BN: scale/shift per feature
__global__ void k_bn(const float* __restrict__ stats, const float* __restrict__ g,
                     const float* __restrict__ beta, float* __restrict__ ss, float invN) {
    int f = threadIdx.x;  // 64 threads
    float mean = stats[f] * invN;
    float var = stats[64 + f] * invN - mean * mean;
    float inv = rsqrtf(var + BN_EPS);
    float sc = g[f] * inv;
    ss[f] = sc;
    ss[64 + f] = beta[f] - mean * sc;
}

// normalize in place + segmented pooled sum (batch is sorted)
__global__ __launch_bounds__(256) void k_norm(float* __restrict__ h, const float* __restrict__ ss,
                                              const int* __restrict__ batch, float* __restrict__ pool,
                                              int layer, int N) {
    int lane = threadIdx.x & 63;
    int wid = (blockIdx.x * blockDim.x + threadIdx.x) >> 6;
    int base = wid * 16;
    if (base >= N) return;
    float sc = ss[lane], sh = ss[64 + lane];
    int curb = -1;
    float acc = 0.f;
    int end = min(base + 16, N);
    for (int n = base; n < end; n++) {
        float v = fmaf(h[(size_t)n * HD + lane], sc, sh);
        h[(size_t)n * HD + lane] = v;
        int b = batch[n];
        if (b != curb) {
            if (curb >= 0) atomicAdd(&pool[(size_t)curb * 192 + layer * HD + lane], acc);
            curb = b;
            acc = v;
        } else {
            acc += v;
        }
    }
    if (curb >= 0) atomicAdd(&pool[(size_t)curb * 192 + layer * HD + lane], acc);
}

extern "C" void kernel_launch(void* const* d_in, const int* in_sizes, int n_in,
                              void* d_out, int out_size, void* d_ws, size_t ws_size,
                              hipStream_t stream) {
    const int N = in_sizes[0] / HD;             // 100000
    const int E = in_sizes[1] / 2;              // 1000000
    const int G = (out_size - N * HD) / 192;    // 512

    const float* x = (const float*)d_in[0];
    const int* ei = (const int*)d_in[1];
    const int* src = ei;
    const int* dst = ei + E;
    const int* batch = (const int*)d_in[2];
    const float* W[3]    = {(const float*)d_in[3], (const float*)d_in[7],  (const float*)d_in[11]};
    const float* bias[3] = {(const float*)d_in[4], (const float*)d_in[8],  (const float*)d_in[12]};
    const float* gam[3]  = {(const float*)d_in[5], (const float*)d_in[9],  (const float*)d_in[13]};
    const float* bet[3]  = {(const float*)d_in[6], (const float*)d_in[10], (const float*)d_in[14]};

    char* ws = (char*)d_ws;
    size_t off = 0;
    auto alloc = [&](size_t bytes) -> void* {
        void* p = ws + off;
        off = (off + bytes + 255) & ~(size_t)255;
        return p;
    };
    int* deg     = (int*)alloc((size_t)N * 4);
    float* dinv  = (float*)alloc((size_t)N * 4);
    int* rowp    = (int*)alloc((size_t)(N + 1) * 4);
    int* cur     = (int*)alloc((size_t)N * 4);
    int* bsums   = (int*)alloc(512 * 4);
    float2* ed   = (float2*)alloc((size_t)E * 8);
    float* hW    = (float*)alloc((size_t)N * HD * 4);
    float* stats = (float*)alloc(3 * 128 * 4);
    float* ss    = (float*)alloc(128 * 4);
    (void)ws_size;

    float* pool = (float*)d_out;                      // [G,192]
    float* hbuf = (float*)d_out + (size_t)G * 192;    // [N,64] — final h lands here

    hipMemsetAsync(deg, 0, (size_t)N * 4, stream);
    hipMemsetAsync(cur, 0, (size_t)N * 4, stream);
    hipMemsetAsync(stats, 0, 3 * 128 * 4, stream);
    hipMemsetAsync(pool, 0, (size_t)G * 192 * 4, stream);

    int nb = (N + 255) / 256;
    k_deg<<<(E + 255) / 256, 256, 0, stream>>>(dst, deg, E);
    k_dinv<<<nb, 256, 0, stream>>>(deg, dinv, N);
    k_scan1<<<nb, 256, 0, stream>>>(deg, rowp, bsums, N);
    k_scan2<<<1, 512, 0, stream>>>(bsums, nb);
    k_scan3<<<nb, 256, 0, stream>>>(rowp, deg, bsums, N, E);
    k_fill<<<(E + 255) / 256, 256, 0, stream>>>(src, dst, dinv, rowp, cur, ed, E);

    const float* hin = x;
    for (int l = 0; l < 3; l++) {
        k_gemm<<<1024, 256, 0, stream>>>(hin, W[l], hW, N);
        k_agg<<<2048, 256, 0, stream>>>(rowp, ed, dinv, hW, bias[l], hbuf, stats + l * 128, N);
        k_bn<<<1, 64, 0, stream>>>(stats + l * 128, gam[l], bet[l], ss, 1.0f / (float)N);
        int waves = (N + 15) / 16;
        int blocks = (waves + 3) / 4;
        k_norm<<<blocks, 256, 0, stream>>>(hbuf, ss, batch, pool, l, N);
        hin = hbuf;
    }
}

// Round 2
// 674.120 us; speedup vs baseline: 1.1913x; 1.1913x over previous
//
#include <hip/hip_runtime.h>

#define HD 64
#define BN_EPS 1e-5f

// ---------- CSR construction ----------

__global__ void k_deg(const int* __restrict__ dst, int* __restrict__ deg, int E) {
    int e = blockIdx.x * blockDim.x + threadIdx.x;
    if (e < E) atomicAdd(&deg[dst[e]], 1);
}

__global__ void k_dinv(const int* __restrict__ deg, float* __restrict__ dinv, int N) {
    int i = blockIdx.x * blockDim.x + threadIdx.x;
    if (i < N) dinv[i] = rsqrtf((float)(deg[i] + 1));  // +1 self-loop
}

__global__ void k_scan1(const int* __restrict__ deg, int* __restrict__ incl,
                        int* __restrict__ bsums, int N) {
    __shared__ int s[256];
    int tid = threadIdx.x;
    int i = blockIdx.x * 256 + tid;
    int v = (i < N) ? deg[i] : 0;
    s[tid] = v;
    __syncthreads();
    for (int off = 1; off < 256; off <<= 1) {
        int t = (tid >= off) ? s[tid - off] : 0;
        __syncthreads();
        s[tid] += t;
        __syncthreads();
    }
    if (i < N) incl[i] = s[tid];
    if (tid == 255) bsums[blockIdx.x] = s[255];
}

__global__ void k_scan2(int* bsums, int nb) {
    __shared__ int s[512];
    int tid = threadIdx.x;
    int own = (tid < nb) ? bsums[tid] : 0;
    s[tid] = own;
    __syncthreads();
    for (int off = 1; off < 512; off <<= 1) {
        int t = (tid >= off) ? s[tid - off] : 0;
        __syncthreads();
        s[tid] += t;
        __syncthreads();
    }
    if (tid < nb) bsums[tid] = s[tid] - own;  // exclusive
}

__global__ void k_scan3(int* __restrict__ rowp, const int* __restrict__ deg,
                        const int* __restrict__ bsums, int N, int E) {
    int i = blockIdx.x * 256 + threadIdx.x;
    if (i < N) rowp[i] = rowp[i] - deg[i] + bsums[blockIdx.x];  // global exclusive
    if (i == 0) rowp[N] = E;
}

__global__ void k_fill(const int* __restrict__ src, const int* __restrict__ dst,
                       const float* __restrict__ dinv, const int* __restrict__ rowp,
                       int* __restrict__ cur, float2* __restrict__ ed, int E) {
    int e = blockIdx.x * blockDim.x + threadIdx.x;
    if (e >= E) return;
    int s = src[e], d = dst[e];
    float nrm = dinv[s] * dinv[d];
    int pos = rowp[d] + atomicAdd(&cur[d], 1);
    ed[pos] = make_float2(__int_as_float(s), nrm);
}

// per-graph node counts via binary search on sorted batch (no atomics)
__global__ void k_gcnt(const int* __restrict__ batch, int* __restrict__ cnt, int N, int G) {
    int g = blockIdx.x * blockDim.x + threadIdx.x;
    if (g >= G) return;
    int lo = 0, hi = N;
    while (lo < hi) { int mid = (lo + hi) >> 1; if (batch[mid] < g) lo = mid + 1; else hi = mid; }
    int lo2 = lo, hi2 = N;
    while (lo2 < hi2) { int mid = (lo2 + hi2) >> 1; if (batch[mid] < g + 1) lo2 = mid + 1; else hi2 = mid; }
    cnt[g] = lo2 - lo;
}

// ---------- per-layer kernels ----------

// Out[i][f] = sum_k A[i][k] * W[f][k] + cb[f]   (h @ W'^T + c), W' held in regs
__global__ __launch_bounds__(256) void k_gemm(const float* __restrict__ A,
                                              const float* __restrict__ W,
                                              const float* __restrict__ cb,
                                              float* __restrict__ Out, int N) {
    int lane = threadIdx.x & 63;
    float w[64];
    const float4* Wv = (const float4*)(W + lane * HD);
#pragma unroll
    for (int kk = 0; kk < 16; kk++) {
        float4 t = Wv[kk];
        w[4 * kk] = t.x; w[4 * kk + 1] = t.y; w[4 * kk + 2] = t.z; w[4 * kk + 3] = t.w;
    }
    float cv = cb ? cb[lane] : 0.f;
    int wid = (blockIdx.x * blockDim.x + threadIdx.x) >> 6;
    int nw = (gridDim.x * blockDim.x) >> 6;
    for (int i = wid; i < N; i += nw) {
        const float4* Av = (const float4*)(A + (size_t)i * HD);
        float a0 = cv, a1 = 0.f, a2 = 0.f, a3 = 0.f;
#pragma unroll
        for (int kk = 0; kk < 16; kk++) {
            float4 hv = Av[kk];  // wave-uniform broadcast load
            a0 = fmaf(hv.x, w[4 * kk], a0);
            a1 = fmaf(hv.y, w[4 * kk + 1], a1);
            a2 = fmaf(hv.z, w[4 * kk + 2], a2);
            a3 = fmaf(hv.w, w[4 * kk + 3], a3);
        }
        Out[(size_t)i * HD + lane] = (a0 + a1) + (a2 + a3);
    }
}

// one wave per contiguous node chunk: gather CSR neighbors (8-deep MLP via
// lane-parallel edge load + shfl broadcast), +bias, relu, write raw h,
// BN partial sums, raw per-graph pooled sums (batch sorted -> run flush)
__global__ __launch_bounds__(256) void k_agg(const int* __restrict__ rowp,
                                             const float2* __restrict__ ed,
                                             const float* __restrict__ dinv,
                                             const float* __restrict__ hW,
                                             const float* __restrict__ bias,
                                             const int* __restrict__ batch,
                                             float* __restrict__ out,
                                             float* __restrict__ stats,
                                             float* __restrict__ praw,
                                             int N, int chunk) {
    int lane = threadIdx.x & 63;
    int wid = (blockIdx.x * blockDim.x + threadIdx.x) >> 6;
    int i0 = wid * chunk;
    int i1 = min(i0 + chunk, N);
    float bv = bias[lane];
    float bsum = 0.f, bsq = 0.f;
    int curb = -1;
    float accp = 0.f;
    for (int i = i0; i < i1; i++) {
        int rs = rowp[i], re = rowp[i + 1];
        float di = dinv[i];
        float acc = di * di * hW[(size_t)i * HD + lane];  // self loop
        for (int base = rs; base < re; base += 64) {
            int cnt = min(64, re - base);
            float2 m = (base + lane < re) ? ed[base + lane] : make_float2(__int_as_float(0), 0.f);
            int si = __float_as_int(m.x);
            float wv = m.y;
            int j = 0;
            for (; j + 8 <= cnt; j += 8) {
                int s0 = __shfl(si, j + 0), s1 = __shfl(si, j + 1);
                int s2 = __shfl(si, j + 2), s3 = __shfl(si, j + 3);
                int s4 = __shfl(si, j + 4), s5 = __shfl(si, j + 5);
                int s6 = __shfl(si, j + 6), s7 = __shfl(si, j + 7);
                float w0 = __shfl(wv, j + 0), w1 = __shfl(wv, j + 1);
                float w2 = __shfl(wv, j + 2), w3 = __shfl(wv, j + 3);
                float w4 = __shfl(wv, j + 4), w5 = __shfl(wv, j + 5);
                float w6 = __shfl(wv, j + 6), w7 = __shfl(wv, j + 7);
                float v0 = hW[(size_t)s0 * HD + lane];
                float v1 = hW[(size_t)s1 * HD + lane];
                float v2 = hW[(size_t)s2 * HD + lane];
                float v3 = hW[(size_t)s3 * HD + lane];
                float v4 = hW[(size_t)s4 * HD + lane];
                float v5 = hW[(size_t)s5 * HD + lane];
                float v6 = hW[(size_t)s6 * HD + lane];
                float v7 = hW[(size_t)s7 * HD + lane];
                acc = fmaf(w0, v0, acc); acc = fmaf(w1, v1, acc);
                acc = fmaf(w2, v2, acc); acc = fmaf(w3, v3, acc);
                acc = fmaf(w4, v4, acc); acc = fmaf(w5, v5, acc);
                acc = fmaf(w6, v6, acc); acc = fmaf(w7, v7, acc);
            }
            for (; j < cnt; j++) {
                int s = __shfl(si, j);
                float w = __shfl(wv, j);
                acc = fmaf(w, hW[(size_t)s * HD + lane], acc);
            }
        }
        acc += bv;
        acc = fmaxf(acc, 0.f);
        out[(size_t)i * HD + lane] = acc;
        bsum += acc;
        bsq = fmaf(acc, acc, bsq);
        int b = batch[i];  // wave-uniform
        if (b != curb) {
            if (curb >= 0) atomicAdd(&praw[(size_t)curb * HD + lane], accp);
            curb = b;
            accp = acc;
        } else {
            accp += acc;
        }
    }
    if (curb >= 0) atomicAdd(&praw[(size_t)curb * HD + lane], accp);
    __shared__ float r1[256], r2[256];
    r1[threadIdx.x] = bsum;
    r2[threadIdx.x] = bsq;
    __syncthreads();
    if (threadIdx.x < 64) {
        float a = r1[threadIdx.x] + r1[threadIdx.x + 64] + r1[threadIdx.x + 128] + r1[threadIdx.x + 192];
        float b = r2[threadIdx.x] + r2[threadIdx.x + 64] + r2[threadIdx.x + 128] + r2[threadIdx.x + 192];
        atomicAdd(&stats[threadIdx.x], a);
        atomicAdd(&stats[64 + threadIdx.x], b);
    }
}

// finalize BN: per-feature scale sc and shift sh
__global__ void k_bn(const float* __restrict__ stats, const float* __restrict__ g,
                     const float* __restrict__ beta, float* __restrict__ ss, float invN) {
    int f = threadIdx.x;  // 64 threads
    float mean = stats[f] * invN;
    float var = stats[64 + f] * invN - mean * mean;
    float inv = rsqrtf(var + BN_EPS);
    float sc = g[f] * inv;
    ss[f] = sc;
    ss[64 + f] = beta[f] - mean * sc;
}

// fold BN affine of previous layer into next layer's weights:
// Wf[f][k] = W[f][k]*sc[k];  cf[f] = sum_k sh[k]*W[f][k]
__global__ void k_fold(const float* __restrict__ W, const float* __restrict__ ss,
                       float* __restrict__ Wf, float* __restrict__ cf) {
    int f = threadIdx.x;  // 64
    float c = 0.f;
    for (int k = 0; k < HD; k++) {
        float w = W[f * HD + k];
        Wf[f * HD + k] = w * ss[k];
        c = fmaf(ss[64 + k], w, c);
    }
    cf[f] = c;
}

// normalize final-layer h in place (float4 vectorized)
__global__ __launch_bounds__(256) void k_final(float* __restrict__ h,
                                               const float* __restrict__ ss, int nquads) {
    int idx = blockIdx.x * blockDim.x + threadIdx.x;
    if (idx >= nquads) return;
    float4* h4 = (float4*)h;
    float4 v = h4[idx];
    int f0 = (idx * 4) & 63;
    v.x = fmaf(v.x, ss[f0 + 0], ss[64 + f0 + 0]);
    v.y = fmaf(v.y, ss[f0 + 1], ss[64 + f0 + 1]);
    v.z = fmaf(v.z, ss[f0 + 2], ss[64 + f0 + 2]);
    v.w = fmaf(v.w, ss[f0 + 3], ss[64 + f0 + 3]);
    h4[idx] = v;
}

// pool[g][l*64+f] = sc_l[f]*praw[l][g][f] + cnt[g]*sh_l[f]
__global__ void k_poolfin(const float* __restrict__ praw, const float* __restrict__ ss_all,
                          const int* __restrict__ cnt, float* __restrict__ pool, int G) {
    int idx = blockIdx.x * blockDim.x + threadIdx.x;
    if (idx >= G * 192) return;
    int g = idx / 192;
    int r = idx - g * 192;
    int l = r >> 6;
    int f = r & 63;
    const float* ss = ss_all + l * 128;
    float v = praw[((size_t)l * G + g) * HD + f];
    pool[idx] = fmaf(ss[f], v, (float)cnt[g] * ss[64 + f]);
}

extern "C" void kernel_launch(void* const* d_in, const int* in_sizes, int n_in,
                              void* d_out, int out_size, void* d_ws, size_t ws_size,
                              hipStream_t stream) {
    const int N = in_sizes[0] / HD;             // 100000
    const int E = in_sizes[1] / 2;              // 1000000
    const int G = (out_size - N * HD) / 192;    // 512

    const float* x = (const float*)d_in[0];
    const int* ei = (const int*)d_in[1];
    const int* src = ei;
    const int* dst = ei + E;
    const int* batch = (const int*)d_in[2];
    const float* W[3]    = {(const float*)d_in[3], (const float*)d_in[7],  (const float*)d_in[11]};
    const float* bias[3] = {(const float*)d_in[4], (const float*)d_in[8],  (const float*)d_in[12]};
    const float* gam[3]  = {(const float*)d_in[5], (const float*)d_in[9],  (const float*)d_in[13]};
    const float* bet[3]  = {(const float*)d_in[6], (const float*)d_in[10], (const float*)d_in[14]};

    char* ws = (char*)d_ws;
    size_t off = 0;
    auto alloc = [&](size_t bytes) -> void* {
        void* p = ws + off;
        off = (off + bytes + 255) & ~(size_t)255;
        return p;
    };
    int* deg     = (int*)alloc((size_t)N * 4);
    float* dinv  = (float*)alloc((size_t)N * 4);
    int* rowp    = (int*)alloc((size_t)(N + 1) * 4);
    int* cur     = (int*)alloc((size_t)N * 4);
    int* bsums   = (int*)alloc(512 * 4);
    float2* ed   = (float2*)alloc((size_t)E * 8);
    float* hW    = (float*)alloc((size_t)N * HD * 4);
    float* stats = (float*)alloc(3 * 128 * 4);
    float* ss    = (float*)alloc(3 * 128 * 4);
    float* Wf    = (float*)alloc(2 * HD * HD * 4);
    float* cf    = (float*)alloc(2 * HD * 4);
    float* praw  = (float*)alloc((size_t)3 * G * HD * 4);
    int* gcnt    = (int*)alloc((size_t)G * 4);
    (void)ws_size;

    float* pool = (float*)d_out;                      // [G,192]
    float* hbuf = (float*)d_out + (size_t)G * 192;    // [N,64] raw h; normalized in place at end

    hipMemsetAsync(deg, 0, (size_t)N * 4, stream);
    hipMemsetAsync(cur, 0, (size_t)N * 4, stream);
    hipMemsetAsync(stats, 0, 3 * 128 * 4, stream);
    hipMemsetAsync(praw, 0, (size_t)3 * G * HD * 4, stream);

    int nb = (N + 255) / 256;
    k_deg<<<(E + 255) / 256, 256, 0, stream>>>(dst, deg, E);
    k_dinv<<<nb, 256, 0, stream>>>(deg, dinv, N);
    k_scan1<<<nb, 256, 0, stream>>>(deg, rowp, bsums, N);
    k_scan2<<<1, 512, 0, stream>>>(bsums, nb);
    k_scan3<<<nb, 256, 0, stream>>>(rowp, deg, bsums, N, E);
    k_fill<<<(E + 255) / 256, 256, 0, stream>>>(src, dst, dinv, rowp, cur, ed, E);
    k_gcnt<<<(G + 255) / 256, 256, 0, stream>>>(batch, gcnt, N, G);

    const int AGG_BLOCKS = 2048;
    const int NW = AGG_BLOCKS * 4;
    const int chunk = (N + NW - 1) / NW;

    const float* hin = x;
    for (int l = 0; l < 3; l++) {
        const float* Wl = (l == 0) ? W[0] : (Wf + (l - 1) * HD * HD);
        const float* cl = (l == 0) ? nullptr : (cf + (l - 1) * HD);
        k_gemm<<<1024, 256, 0, stream>>>(hin, Wl, cl, hW, N);
        k_agg<<<AGG_BLOCKS, 256, 0, stream>>>(rowp, ed, dinv, hW, bias[l], batch,
                                              hbuf, stats + l * 128, praw + (size_t)l * G * HD,
                                              N, chunk);
        k_bn<<<1, 64, 0, stream>>>(stats + l * 128, gam[l], bet[l], ss + l * 128, 1.0f / (float)N);
        if (l < 2) {
            k_fold<<<1, 64, 0, stream>>>(W[l + 1], ss + l * 128, Wf + l * HD * HD, cf + l * HD);
        }
        hin = hbuf;
    }
    int nquads = N * HD / 4;
    k_final<<<(nquads + 255) / 256, 256, 0, stream>>>(hbuf, ss + 2 * 128, nquads);
    k_poolfin<<<(G * 192 + 255) / 256, 256, 0, stream>>>(praw, ss, gcnt, pool, G);
}